// Round 11
// baseline (1277.954 us; speedup 1.0000x reference)
//
#include <hip/hip_runtime.h>
#include <hip/hip_bf16.h>

#define HH 256
#define WW 256
#define NB 16
#define CC 64
#define NL 256
#define HWSZ (HH*WW)
#define EPSV 1e-5f
#define CAST 104   // conva LDS channel stride (shorts)
#define NYK 16     // distinct yk values: 118..133
#define YK0 118

using bf16 = __hip_bfloat16;
using short8  = __attribute__((ext_vector_type(8))) short;
using floatx4 = __attribute__((ext_vector_type(4))) float;

__device__ __forceinline__ ushort f2b(float f){
    bf16 h = __float2bfloat16(f);
    union { bf16 h; ushort u; } cv; cv.h = h; return cv.u;
}
__device__ __forceinline__ float b2fu(ushort u){
    union { unsigned int i; float f; } cv; cv.i = ((unsigned int)u) << 16; return cv.f;
}

// ---------------------------------------------------------------------------
// Weight prep (unchanged).
// ---------------------------------------------------------------------------
__global__ void prep_w_k(const float* __restrict__ wk, const float* __restrict__ wa,
                         ushort* __restrict__ wkb2, ushort* __restrict__ wab2)
{
    int i = blockIdx.x*256 + threadIdx.x;
    const int NWK = 3*9*64*64, NWA = 9*64*96;
    if (i < NWK) {
        int ci = i & 63; int r = i >> 6; int co = r & 63; r >>= 6; int tap = r % 9; int t = r / 9;
        wkb2[i] = f2b(wk[(((size_t)t*64 + co)*64 + ci)*9 + tap]);
    } else if (i < NWK + NWA) {
        int i2 = i - NWK;
        int ci = i2 % 96; int r = i2 / 96; int co = r & 63; int tap = r >> 6;
        float v = 0.f;
        if (ci < 64)      v = wa[((size_t)co*323 + 256 + ci)*9 + tap];
        else if (ci < 67) v = wa[((size_t)co*323 + 320 + (ci-64))*9 + tap];
        wab2[i2] = f2b(v);
    }
}

// ---------------------------------------------------------------------------
// conv0 (unchanged, known-good).
// ---------------------------------------------------------------------------
__global__ __launch_bounds__(256) void conv0_k(
    const float* __restrict__ img, const float* __restrict__ w0,
    const float* __restrict__ bias, const float* __restrict__ gamma,
    const float* __restrict__ beta, const float* __restrict__ mean,
    const float* __restrict__ var, ushort* __restrict__ outp)
{
    __shared__ float s_i[3][18][18];
    __shared__ float s_wv[64*27];
    __shared__ float s_al[64], s_be[64];
    __shared__ ushort __align__(16) s_y[256*72];

    int tid = threadIdx.x;
    int x0 = blockIdx.x*16, y0 = blockIdx.y*16, b = blockIdx.z;
    if (tid < 64) {
        float a = gamma[tid]*rsqrtf(var[tid]+EPSV);
        s_al[tid] = a; s_be[tid] = (bias[tid]-mean[tid])*a + beta[tid];
    }
    for (int c = tid; c < 64*27; c += 256) s_wv[c] = w0[c];
    for (int c = tid; c < 3*18*18; c += 256) {
        int ci = c / 324, pp = c % 324, py = pp/18, px = pp%18;
        int gy = y0-1+py, gx = x0-1+px;
        float v = 0.f;
        if ((unsigned)gy < 256u && (unsigned)gx < 256u)
            v = img[((size_t)b*3 + ci)*HWSZ + gy*256 + gx];
        s_i[ci][py][px] = v;
    }
    __syncthreads();

    int ly = tid >> 4, lx = tid & 15;
    float xv[27];
    #pragma unroll
    for (int ci=0;ci<3;ci++)
      #pragma unroll
      for (int p=0;p<3;p++)
        #pragma unroll
        for (int q=0;q<3;q++)
            xv[ci*9+p*3+q] = s_i[ci][ly+p][lx+q];

    for (int co=0; co<64; co++) {
        float a = 0.f;
        #pragma unroll
        for (int j=0;j<27;j++) a += xv[j]*s_wv[co*27+j];
        s_y[tid*72 + co] = f2b(fmaxf(s_al[co]*a + s_be[co], 0.f));
    }
    __syncthreads();
    size_t obase = (size_t)b*HWSZ*64;
    for (int c = tid; c < 256*8; c += 256) {
        int ci8 = c & 7, px = c >> 3;
        int gy = y0 + (px>>4), gx = x0 + (px&15);
        *(uint4*)&outp[obase + (size_t)(gy*256+gx)*64 + ci8*8] =
            *(const uint4*)&s_y[px*72 + ci8*8];
    }
}

// ---------------------------------------------------------------------------
// Mid conv 64->64, all-global: no input staging, no pre-K barrier.
// B-frags read straight from global NHWC (per-px reads are full 64B lines,
// coalesced); border px handled by exec-masked predication. LDS only for
// the coalesced output repack. 4 blocks/CU.
// ---------------------------------------------------------------------------
__global__ __launch_bounds__(256,4) void convm_k(
    const ushort* __restrict__ in, const ushort* __restrict__ wgt, // [9][64][64]
    ushort* __restrict__ outp,
    const float* __restrict__ gamma, const float* __restrict__ beta,
    const float* __restrict__ mean,  const float* __restrict__ var,
    const float* __restrict__ bias,  float* __restrict__ plane)
{
    __shared__ ushort __align__(16) s_y[256*72];
    __shared__ float s_al[64], s_be[64];

    const int tid = threadIdx.x;
    const int x0 = blockIdx.x*16, y0 = blockIdx.y*16, b = blockIdx.z;
    const int lane = tid & 63, wid = tid >> 6;
    const int n16 = lane & 15, quad = lane >> 4;

    if (tid < 64) {
        float a = gamma[tid]*rsqrtf(var[tid]+EPSV);
        s_al[tid] = a; s_be[tid] = (bias[tid]-mean[tid])*a + beta[tid];
    }

    const size_t ibase = (size_t)b*HWSZ*64;

    floatx4 acc[4][4];
    #pragma unroll
    for (int mi=0;mi<4;mi++)
      #pragma unroll
      for (int ni=0;ni<4;ni++)
        #pragma unroll
        for (int r=0;r<4;r++) acc[mi][ni][r] = 0.f;

    #pragma unroll
    for (int q=0; q<3; q++) {
        const int gx = x0 + n16 + q - 1;
        const bool okx = (unsigned)gx < 256u;
        #pragma unroll
        for (int kc=0; kc<64; kc+=32) {
            short8 bfr[6];
            #pragma unroll
            for (int rr=0; rr<6; rr++) {
                int gy = y0 + wid*4 + rr - 1;
                short8 v;
                #pragma unroll
                for (int e=0;e<8;e++) v[e] = 0;
                if (okx && (unsigned)gy < 256u)
                    v = *(const short8*)&in[ibase + (size_t)(gy*256+gx)*64 + kc + quad*8];
                bfr[rr] = v;
            }
            short8 af[3][4];
            #pragma unroll
            for (int p=0;p<3;p++)
              #pragma unroll
              for (int mi=0;mi<4;mi++)
                af[p][mi] = *(const short8*)&wgt[((size_t)(p*3+q)*64 + mi*16+n16)*64 + kc + quad*8];
            #pragma unroll
            for (int p=0;p<3;p++)
              #pragma unroll
              for (int mi=0;mi<4;mi++)
                #pragma unroll
                for (int ni=0;ni<4;ni++)
                  acc[mi][ni] = __builtin_amdgcn_mfma_f32_16x16x32_bf16(
                      af[p][mi], bfr[ni+p], acc[mi][ni], 0, 0, 0);
        }
    }
    __syncthreads();   // s_al visible; s_y region ready

    #pragma unroll
    for (int mi=0;mi<4;mi++)
      #pragma unroll
      for (int ni=0;ni<4;ni++) {
        int px = (wid*4+ni)*16 + n16;
        int cob = mi*16 + quad*4;
        ushort u[4];
        #pragma unroll
        for (int r=0;r<4;r++) {
            float y = fmaxf(s_al[cob+r]*acc[mi][ni][r] + s_be[cob+r], 0.f);
            u[r] = f2b(y);
            if (plane && mi==0 && quad==0 && r==0)
                plane[(size_t)b*HWSZ + (y0+wid*4+ni)*256 + x0 + n16] = y;
        }
        uint2 pk; pk.x = (uint)u[0] | ((uint)u[1]<<16); pk.y = (uint)u[2] | ((uint)u[3]<<16);
        *(uint2*)&s_y[px*72 + cob] = pk;
      }
    __syncthreads();
    for (int c = tid; c < 256*8; c += 256) {
        int ci8 = c & 7, px = c >> 3;
        int gy = y0 + (px>>4), gx = x0 + (px&15);
        *(uint4*)&outp[ibase + (size_t)(gy*256+gx)*64 + ci8*8] =
            *(const uint4*)&s_y[px*72 + ci8*8];
    }
}

// ---------------------------------------------------------------------------
// conva (unchanged from R10).
// ---------------------------------------------------------------------------
__global__ __launch_bounds__(256,2) void conva_k(
    const ushort* __restrict__ enc, const float* __restrict__ img,
    const float* __restrict__ dplane, const ushort* __restrict__ wgt, // [9][64][96]
    const float* __restrict__ gamma, const float* __restrict__ beta,
    const float* __restrict__ mean,  const float* __restrict__ var,
    const float* __restrict__ bias,
    const float* __restrict__ Tb,    // [b][64][9]
    const float* __restrict__ wf, const float* __restrict__ bfv,
    float* __restrict__ outp)
{
    __shared__ ushort __align__(16) s_x[18*18*CAST];
    __shared__ float s_al[64], s_be[64];
    __shared__ float s_T[64*9];
    __shared__ float s_wf[3*64];
    __shared__ float s_bf[3];

    const int tid = threadIdx.x;
    const int x0 = blockIdx.x*16, y0 = blockIdx.y*16, b = blockIdx.z;

    if (tid < 64) {
        float a = gamma[tid]*rsqrtf(var[tid]+EPSV);
        s_al[tid] = a; s_be[tid] = (bias[tid]-mean[tid])*a + beta[tid];
    }
    if (tid < 192) s_wf[tid] = wf[tid];
    if (tid < 3)   s_bf[tid] = bfv[tid];
    for (int c = tid; c < 64*9; c += 256) s_T[c] = Tb[(size_t)b*576 + c];

    const size_t ibase = (size_t)b*HWSZ*64;
    for (int c = tid; c < 18*18*13; c += 256) {
        int ci8 = c % 13, pp = c / 13;
        int px = pp % 18, py = pp / 18;
        int gy = y0-1+py, gx = x0-1+px;
        bool ok = (unsigned)gy < 256u && (unsigned)gx < 256u;
        uint4 v = make_uint4(0,0,0,0);
        if (ci8 < 8) {
            if (ok) {
                v = *(const uint4*)&enc[ibase + (size_t)(gy*256+gx)*64 + ci8*8];
                if (ci8 == 0) {
                    float d = dplane[(size_t)b*HWSZ + gy*256 + gx];
                    ushort nb = f2b(b2fu((ushort)(v.x & 0xffffu)) + d);
                    v.x = (v.x & 0xffff0000u) | (uint)nb;
                }
            }
        } else if (ci8 == 8 && ok) {
            float i0 = img[((size_t)b*3 + 0)*HWSZ + gy*256 + gx];
            float i1 = img[((size_t)b*3 + 1)*HWSZ + gy*256 + gx];
            float i2 = img[((size_t)b*3 + 2)*HWSZ + gy*256 + gx];
            v.x = (uint)f2b(i0) | ((uint)f2b(i1) << 16);
            v.y = (uint)f2b(i2);
        }
        *(uint4*)&s_x[(py*18+px)*CAST + ci8*8] = v;
    }
    __syncthreads();

    const int lane = tid & 63, wid = tid >> 6;
    const int n16 = lane & 15, quad = lane >> 4;

    floatx4 acc[4][4];
    #pragma unroll
    for (int mi=0;mi<4;mi++)
      #pragma unroll
      for (int ni=0;ni<4;ni++)
        #pragma unroll
        for (int r=0;r<4;r++) acc[mi][ni][r] = 0.f;

    #pragma unroll
    for (int q=0; q<3; q++) {
        #pragma unroll
        for (int kc=0; kc<96; kc+=32) {
            short8 bfr[6];
            #pragma unroll
            for (int rr=0; rr<6; rr++)
                bfr[rr] = *(const short8*)&s_x[((wid*4+rr)*18 + n16+q)*CAST + kc + quad*8];
            short8 af[3][4];
            #pragma unroll
            for (int p=0;p<3;p++)
              #pragma unroll
              for (int mi=0;mi<4;mi++)
                af[p][mi] = *(const short8*)&wgt[((size_t)(p*3+q)*64 + mi*16+n16)*96 + kc + quad*8];
            #pragma unroll
            for (int p=0;p<3;p++)
              #pragma unroll
              for (int mi=0;mi<4;mi++)
                #pragma unroll
                for (int ni=0;ni<4;ni++)
                  acc[mi][ni] = __builtin_amdgcn_mfma_f32_16x16x32_bf16(
                      af[p][mi], bfr[ni+p], acc[mi][ni], 0, 0, 0);
        }
    }

    float po[3][4];
    #pragma unroll
    for (int o=0;o<3;o++)
      #pragma unroll
      for (int ni=0;ni<4;ni++) po[o][ni] = 0.f;

    #pragma unroll
    for (int mi=0;mi<4;mi++) {
        int cob = mi*16 + quad*4;
        #pragma unroll
        for (int r=0;r<4;r++) {
            int co = cob + r;
            float al = s_al[co], be = s_be[co];
            const float* t = &s_T[co*9];
            float w0f = s_wf[0*64+co], w1f = s_wf[1*64+co], w2f = s_wf[2*64+co];
            #pragma unroll
            for (int ni=0;ni<4;ni++) {
                int h = y0 + wid*4 + ni, w = x0 + n16;
                float tv = t[0];
                if (h==0)   tv -= t[1];
                if (h==255) tv -= t[2];
                if (w==0)   tv -= t[3];
                if (w==255) tv -= t[4];
                if (h==0   && w==0)   tv += t[5];
                if (h==0   && w==255) tv += t[6];
                if (h==255 && w==0)   tv += t[7];
                if (h==255 && w==255) tv += t[8];
                float y = fmaxf(al*(acc[mi][ni][r] + tv) + be, 0.f);
                po[0][ni] += w0f*y; po[1][ni] += w1f*y; po[2][ni] += w2f*y;
            }
        }
    }
    #pragma unroll
    for (int o=0;o<3;o++)
      #pragma unroll
      for (int ni=0;ni<4;ni++) {
        float pv = po[o][ni];
        pv += __shfl_xor(pv, 16, 64);
        pv += __shfl_xor(pv, 32, 64);
        if (quad == o) {
            int h = y0 + wid*4 + ni, w = x0 + n16;
            outp[((size_t)b*3 + o)*HWSZ + h*256 + w] = pv + s_bf[o];
        }
      }
}

// ---------------------------------------------------------------------------
// msgterm / idx (unchanged)
// ---------------------------------------------------------------------------
__global__ __launch_bounds__(256) void msgterm_k(const float* __restrict__ msg,
                                                 const float* __restrict__ wa,
                                                 float* __restrict__ Tbuf)
{
    __shared__ float red[256];
    int b = blockIdx.x, o = blockIdx.y, l = threadIdx.x;
    float m = msg[b*NL + l];
    float wv[9];
    #pragma unroll
    for (int t=0;t<9;t++) wv[t] = wa[((size_t)o*323 + l)*9 + t] * m;
    float comp[9];
    comp[0] = wv[0]+wv[1]+wv[2]+wv[3]+wv[4]+wv[5]+wv[6]+wv[7]+wv[8];
    comp[1] = wv[0]+wv[1]+wv[2];
    comp[2] = wv[6]+wv[7]+wv[8];
    comp[3] = wv[0]+wv[3]+wv[6];
    comp[4] = wv[2]+wv[5]+wv[8];
    comp[5] = wv[0]; comp[6]=wv[2]; comp[7]=wv[6]; comp[8]=wv[8];
    for (int cpi=0;cpi<9;cpi++){
        red[l] = comp[cpi];
        __syncthreads();
        for (int s=128;s>0;s>>=1){ if (l<s) red[l]+=red[l+s]; __syncthreads(); }
        if (l==0) Tbuf[((size_t)b*CC+o)*9+cpi] = red[0];
        __syncthreads();
    }
}

__global__ void build_idx_k(int* __restrict__ idx)
{
    if (threadIdx.x==0 && blockIdx.x==0) {
        int n=0;
        for (int i=-10;i<=10;i++)
            for (int j=-10;j<=10;j++) {
                if (n>=NL) return;
                if (i*i+j*j<=100) { idx[2*n]=128+i; idx[2*n+1]=128+j; n++; }
            }
    }
}

// ---------------------------------------------------------------------------
// Separable watermark DFT pipeline (unchanged from R10).
// ---------------------------------------------------------------------------
__global__ __launch_bounds__(256) void colA_k(const float* __restrict__ plane,
                                              float* __restrict__ Cbuf)
{
    __shared__ float twc[256], tws[256];
    int t = blockIdx.x, b = blockIdx.y, w = threadIdx.x;
    float sv, cv;
    __sincosf(6.283185307179586f * (float)w / 256.0f, &sv, &cv);
    twc[w]=cv; tws[w]=sv;
    __syncthreads();
    int yk = YK0 + t;
    const float* pb = &plane[(size_t)b*HWSZ];
    int m = 0;
    float fr=0.f, fi=0.f;
    for (int h=0; h<256; h++) {
        float xv = pb[h*256 + w];
        fr += xv*twc[m];
        fi -= xv*tws[m];
        m = (m + yk) & 255;
    }
    float* Cb = &Cbuf[((size_t)(b*NYK + t)*2)*256];
    Cb[w]       = fr;
    Cb[256 + w] = fi;
}

__global__ __launch_bounds__(256) void freqB_k(const float* __restrict__ Cbuf,
                                               const float* __restrict__ msg,
                                               const int* __restrict__ idx,
                                               float* __restrict__ D)
{
    __shared__ float twc[256], tws[256], red[256];
    int k = blockIdx.x, b = blockIdx.y, w = threadIdx.x;
    float sv, cv;
    __sincosf(6.283185307179586f * (float)w / 256.0f, &sv, &cv);
    twc[w]=cv; tws[w]=sv;
    __syncthreads();
    int yk = idx[2*k], xk = idx[2*k+1];
    int t = yk - YK0;
    const float* Cb = &Cbuf[((size_t)(b*NYK + t)*2)*256];
    float Cr = Cb[w], Ci = Cb[256 + w];
    int ang = (xk*w) & 255;
    float cx = twc[ang], sx = tws[ang];
    float fr = Cr*cx + Ci*sx;
    float fi = Ci*cx - Cr*sx;
    red[w]=fr; __syncthreads();
    for (int s=128;s>0;s>>=1){ if(w<s) red[w]+=red[w+s]; __syncthreads(); }
    float FR = red[0]; __syncthreads();
    red[w]=fi; __syncthreads();
    for (int s=128;s>0;s>>=1){ if(w<s) red[w]+=red[w+s]; __syncthreads(); }
    if (w==0) {
        float FI = red[0];
        float mv = msg[b*NL + k];
        D[((size_t)b*NL + k)*2 + 0] = mv - FR;
        D[((size_t)b*NL + k)*2 + 1] = mv - FI;
    }
}

__global__ __launch_bounds__(256) void rowC_k(const int* __restrict__ idx,
                                              const float* __restrict__ D,
                                              float* __restrict__ Sbuf)
{
    __shared__ float twc[256], tws[256], dr[256], di[256];
    __shared__ int iy[256], ix[256];
    int t = blockIdx.x, b = blockIdx.y, w = threadIdx.x;
    float sv, cv;
    __sincosf(6.283185307179586f * (float)w / 256.0f, &sv, &cv);
    twc[w]=cv; tws[w]=sv;
    dr[w] = D[((size_t)b*NL + w)*2+0];
    di[w] = D[((size_t)b*NL + w)*2+1];
    iy[w] = idx[2*w]; ix[w] = idx[2*w+1];
    __syncthreads();
    int yk = YK0 + t;
    float Sr=0.f, Si=0.f;
    for (int k=0;k<256;k++) {
        if (iy[k] != yk) continue;           // wave-uniform branch
        int ang = (ix[k]*w) & 255;
        float c = twc[ang], s = tws[ang];
        Sr += dr[k]*c - di[k]*s;
        Si += dr[k]*s + di[k]*c;
    }
    float* Sb = &Sbuf[((size_t)(b*NYK + t)*2)*256];
    Sb[w]       = Sr;
    Sb[256 + w] = Si;
}

__global__ __launch_bounds__(256) void applyD_k(const float* __restrict__ Sbuf,
                                                float* __restrict__ dplane)
{
    __shared__ float twc[256], tws[256];
    int h = blockIdx.x, b = blockIdx.y, w = threadIdx.x;
    float sv, cv;
    __sincosf(6.283185307179586f * (float)w / 256.0f, &sv, &cv);
    twc[w]=cv; tws[w]=sv;
    __syncthreads();
    float acc = 0.f;
    #pragma unroll
    for (int t=0;t<NYK;t++) {
        int yk = YK0 + t;
        int ang = (yk*h) & 255;              // wave-uniform
        float cy = twc[ang], sy = tws[ang];
        const float* Sb = &Sbuf[((size_t)(b*NYK + t)*2)*256];
        acc += cy*Sb[w] - sy*Sb[256 + w];
    }
    dplane[(size_t)b*HWSZ + h*256 + w] = acc * (1.0f/65536.0f);
}

// ---------------------------------------------------------------------------
extern "C" void kernel_launch(void* const* d_in, const int* in_sizes, int n_in,
                              void* d_out, int out_size, void* d_ws, size_t ws_size,
                              hipStream_t stream)
{
    const float* image = (const float*)d_in[0];
    const float* msg   = (const float*)d_in[1];
    const float* w0    = (const float*)d_in[2];
    const float* b0    = (const float*)d_in[3];
    const float* g0    = (const float*)d_in[4];
    const float* be0   = (const float*)d_in[5];
    const float* m0    = (const float*)d_in[6];
    const float* v0    = (const float*)d_in[7];
    const float* wk    = (const float*)d_in[8];
    const float* bk    = (const float*)d_in[9];
    const float* gk    = (const float*)d_in[10];
    const float* bek   = (const float*)d_in[11];
    const float* mk    = (const float*)d_in[12];
    const float* vk    = (const float*)d_in[13];
    const float* wa    = (const float*)d_in[14];
    const float* ba    = (const float*)d_in[15];
    const float* ga    = (const float*)d_in[16];
    const float* bea   = (const float*)d_in[17];
    const float* ma    = (const float*)d_in[18];
    const float* va    = (const float*)d_in[19];
    const float* wf    = (const float*)d_in[20];
    const float* bfv   = (const float*)d_in[21];
    float* out = (float*)d_out;

    char* base = (char*)d_ws;
    int*    idx    = (int*)base;                         // 2 KB
    float*  Dbuf   = (float*)(base + (4<<10));           // 32 KB
    float*  Tbuf   = (float*)(base + (64<<10));          // 36 KB
    ushort* wkb2   = (ushort*)(base + (128<<10));        // 216 KB
    ushort* wab2   = (ushort*)(base + (512<<10));        // 108 KB
    float*  plane  = (float*)(base + ((size_t)1<<20));   // 4 MB
    float*  dplane = (float*)(base + ((size_t)6<<20));   // 4 MB
    float*  Cbuf   = (float*)(base + ((size_t)11<<20));  // 512 KB
    float*  Sbuf   = (float*)(base + ((size_t)12<<20));  // 512 KB
    ushort* bufA   = (ushort*)(base + ((size_t)16<<20));

    const size_t perB = (size_t)HWSZ*64*2*2;  // 16.8 MB: both bf16 buffers / batch
    int chunk = 1;
    for (int c = NB; c >= 1; c >>= 1)
        if (((size_t)16<<20) + (size_t)c*perB <= ws_size) { chunk = c; break; }
    ushort* bufB = bufA + (size_t)chunk*HWSZ*64;

    build_idx_k<<<1,64,0,stream>>>(idx);
    msgterm_k<<<dim3(NB,CC),256,0,stream>>>(msg, wa, Tbuf);
    int prep_n = (3*9*64*64 + 9*64*96 + 255)/256;
    prep_w_k<<<prep_n,256,0,stream>>>(wk, wa, wkb2, wab2);

    const size_t WL = (size_t)9*64*64;  // one layer of wkb2

    for (int cs = 0; cs < NB; cs += chunk) {
        dim3 g(16,16,chunk);
        const float* img_c = image + (size_t)cs*3*HWSZ;

        conv0_k<<<g,256,0,stream>>>(img_c, w0, b0, g0, be0, m0, v0, bufA);
        convm_k<<<g,256,0,stream>>>(bufA, wkb2 + 0*WL, bufB,
            gk+0*CC, bek+0*CC, mk+0*CC, vk+0*CC, bk+0*CC, nullptr);
        convm_k<<<g,256,0,stream>>>(bufB, wkb2 + 1*WL, bufA,
            gk+1*CC, bek+1*CC, mk+1*CC, vk+1*CC, bk+1*CC, nullptr);
        convm_k<<<g,256,0,stream>>>(bufA, wkb2 + 2*WL, bufB,
            gk+2*CC, bek+2*CC, mk+2*CC, vk+2*CC, bk+2*CC, plane);

        // separable watermark DFT (forward + inverse)
        colA_k<<<dim3(NYK,chunk),256,0,stream>>>(plane, Cbuf);
        freqB_k<<<dim3(NL,chunk),256,0,stream>>>(Cbuf, msg + (size_t)cs*NL, idx, Dbuf);
        rowC_k<<<dim3(NYK,chunk),256,0,stream>>>(idx, Dbuf, Sbuf);
        applyD_k<<<dim3(HH,chunk),256,0,stream>>>(Sbuf, dplane);

        conva_k<<<g,256,0,stream>>>(bufB, img_c, dplane, wab2,
            ga, bea, ma, va, ba, Tbuf + (size_t)cs*CC*9, wf, bfv,
            out + (size_t)cs*3*HWSZ);
    }
}

// Round 12
// 1143.623 us; speedup vs baseline: 1.1175x; 1.1175x over previous
//
#include <hip/hip_runtime.h>
#include <hip/hip_bf16.h>

#define HH 256
#define WW 256
#define NB 16
#define CC 64
#define NL 256
#define HWSZ (HH*WW)
#define EPSV 1e-5f
#define CAST 104   // conva LDS channel stride (shorts)
#define NYK 16     // distinct yk values: 118..133
#define YK0 118

using bf16 = __hip_bfloat16;
using short8  = __attribute__((ext_vector_type(8))) short;
using floatx4 = __attribute__((ext_vector_type(4))) float;

__device__ __forceinline__ ushort f2b(float f){
    bf16 h = __float2bfloat16(f);
    union { bf16 h; ushort u; } cv; cv.h = h; return cv.u;
}
__device__ __forceinline__ float b2fu(ushort u){
    union { unsigned int i; float f; } cv; cv.i = ((unsigned int)u) << 16; return cv.f;
}

// ---------------------------------------------------------------------------
// Weight prep (unchanged).
// ---------------------------------------------------------------------------
__global__ void prep_w_k(const float* __restrict__ wk, const float* __restrict__ wa,
                         ushort* __restrict__ wkb2, ushort* __restrict__ wab2)
{
    int i = blockIdx.x*256 + threadIdx.x;
    const int NWK = 3*9*64*64, NWA = 9*64*96;
    if (i < NWK) {
        int ci = i & 63; int r = i >> 6; int co = r & 63; r >>= 6; int tap = r % 9; int t = r / 9;
        wkb2[i] = f2b(wk[(((size_t)t*64 + co)*64 + ci)*9 + tap]);
    } else if (i < NWK + NWA) {
        int i2 = i - NWK;
        int ci = i2 % 96; int r = i2 / 96; int co = r & 63; int tap = r >> 6;
        float v = 0.f;
        if (ci < 64)      v = wa[((size_t)co*323 + 256 + ci)*9 + tap];
        else if (ci < 67) v = wa[((size_t)co*323 + 320 + (ci-64))*9 + tap];
        wab2[i2] = f2b(v);
    }
}

// ---------------------------------------------------------------------------
// conv0 (known-good, unchanged).
// ---------------------------------------------------------------------------
__global__ __launch_bounds__(256) void conv0_k(
    const float* __restrict__ img, const float* __restrict__ w0,
    const float* __restrict__ bias, const float* __restrict__ gamma,
    const float* __restrict__ beta, const float* __restrict__ mean,
    const float* __restrict__ var, ushort* __restrict__ outp)
{
    __shared__ float s_i[3][18][18];
    __shared__ float s_wv[64*27];
    __shared__ float s_al[64], s_be[64];
    __shared__ ushort __align__(16) s_y[256*72];

    int tid = threadIdx.x;
    int x0 = blockIdx.x*16, y0 = blockIdx.y*16, b = blockIdx.z;
    if (tid < 64) {
        float a = gamma[tid]*rsqrtf(var[tid]+EPSV);
        s_al[tid] = a; s_be[tid] = (bias[tid]-mean[tid])*a + beta[tid];
    }
    for (int c = tid; c < 64*27; c += 256) s_wv[c] = w0[c];
    for (int c = tid; c < 3*18*18; c += 256) {
        int ci = c / 324, pp = c % 324, py = pp/18, px = pp%18;
        int gy = y0-1+py, gx = x0-1+px;
        float v = 0.f;
        if ((unsigned)gy < 256u && (unsigned)gx < 256u)
            v = img[((size_t)b*3 + ci)*HWSZ + gy*256 + gx];
        s_i[ci][py][px] = v;
    }
    __syncthreads();

    int ly = tid >> 4, lx = tid & 15;
    float xv[27];
    #pragma unroll
    for (int ci=0;ci<3;ci++)
      #pragma unroll
      for (int p=0;p<3;p++)
        #pragma unroll
        for (int q=0;q<3;q++)
            xv[ci*9+p*3+q] = s_i[ci][ly+p][lx+q];

    for (int co=0; co<64; co++) {
        float a = 0.f;
        #pragma unroll
        for (int j=0;j<27;j++) a += xv[j]*s_wv[co*27+j];
        s_y[tid*72 + co] = f2b(fmaxf(s_al[co]*a + s_be[co], 0.f));
    }
    __syncthreads();
    size_t obase = (size_t)b*HWSZ*64;
    for (int c = tid; c < 256*8; c += 256) {
        int ci8 = c & 7, px = c >> 3;
        int gy = y0 + (px>>4), gx = x0 + (px&15);
        *(uint4*)&outp[obase + (size_t)(gy*256+gx)*64 + ci8*8] =
            *(const uint4*)&s_y[px*72 + ci8*8];
    }
}

// ---------------------------------------------------------------------------
// Mid conv 64->64 (R10 LDS version, measured ~100us — reverted from R11's
// all-global experiment which starved the register file at launch_bounds 4).
// ---------------------------------------------------------------------------
__global__ __launch_bounds__(256,3) void convm_k(
    const ushort* __restrict__ in, const ushort* __restrict__ wgt, // [9][64][64]
    ushort* __restrict__ outp,
    const float* __restrict__ gamma, const float* __restrict__ beta,
    const float* __restrict__ mean,  const float* __restrict__ var,
    const float* __restrict__ bias,  float* __restrict__ plane)
{
    __shared__ ushort __align__(16) s_x[18*18*72];
    __shared__ float s_al[64], s_be[64];

    const int tid = threadIdx.x;
    const int x0 = blockIdx.x*16, y0 = blockIdx.y*16, b = blockIdx.z;

    if (tid < 64) {
        float a = gamma[tid]*rsqrtf(var[tid]+EPSV);
        s_al[tid] = a; s_be[tid] = (bias[tid]-mean[tid])*a + beta[tid];
    }
    const size_t ibase = (size_t)b*HWSZ*64;
    for (int c = tid; c < 18*18*8; c += 256) {
        int ci8 = c & 7, pp = c >> 3;
        int px = pp % 18, py = pp / 18;
        int gy = y0-1+py, gx = x0-1+px;
        uint4 v = make_uint4(0,0,0,0);
        if ((unsigned)gy < 256u && (unsigned)gx < 256u)
            v = *(const uint4*)&in[ibase + (size_t)(gy*256+gx)*64 + ci8*8];
        *(uint4*)&s_x[(py*18+px)*72 + ci8*8] = v;
    }
    __syncthreads();

    const int lane = tid & 63, wid = tid >> 6;
    const int n16 = lane & 15, quad = lane >> 4;

    floatx4 acc[4][4];
    #pragma unroll
    for (int mi=0;mi<4;mi++)
      #pragma unroll
      for (int ni=0;ni<4;ni++)
        #pragma unroll
        for (int r=0;r<4;r++) acc[mi][ni][r] = 0.f;

    #pragma unroll
    for (int q=0; q<3; q++) {
        #pragma unroll
        for (int kc=0; kc<64; kc+=32) {
            short8 bfr[6];
            #pragma unroll
            for (int rr=0; rr<6; rr++)
                bfr[rr] = *(const short8*)&s_x[((wid*4+rr)*18 + n16+q)*72 + kc + quad*8];
            short8 af[3][4];
            #pragma unroll
            for (int p=0;p<3;p++)
              #pragma unroll
              for (int mi=0;mi<4;mi++)
                af[p][mi] = *(const short8*)&wgt[((size_t)(p*3+q)*64 + mi*16+n16)*64 + kc + quad*8];
            #pragma unroll
            for (int p=0;p<3;p++)
              #pragma unroll
              for (int mi=0;mi<4;mi++)
                #pragma unroll
                for (int ni=0;ni<4;ni++)
                  acc[mi][ni] = __builtin_amdgcn_mfma_f32_16x16x32_bf16(
                      af[p][mi], bfr[ni+p], acc[mi][ni], 0, 0, 0);
        }
    }
    __syncthreads();

    ushort* s_y = s_x;
    #pragma unroll
    for (int mi=0;mi<4;mi++)
      #pragma unroll
      for (int ni=0;ni<4;ni++) {
        int px = (wid*4+ni)*16 + n16;
        int cob = mi*16 + quad*4;
        ushort u[4];
        #pragma unroll
        for (int r=0;r<4;r++) {
            float y = fmaxf(s_al[cob+r]*acc[mi][ni][r] + s_be[cob+r], 0.f);
            u[r] = f2b(y);
            if (plane && mi==0 && quad==0 && r==0)
                plane[(size_t)b*HWSZ + (y0+wid*4+ni)*256 + x0 + n16] = y;
        }
        uint2 pk; pk.x = (uint)u[0] | ((uint)u[1]<<16); pk.y = (uint)u[2] | ((uint)u[3]<<16);
        *(uint2*)&s_y[px*72 + cob] = pk;
      }
    __syncthreads();
    for (int c = tid; c < 256*8; c += 256) {
        int ci8 = c & 7, px = c >> 3;
        int gy = y0 + (px>>4), gx = x0 + (px&15);
        *(uint4*)&outp[ibase + (size_t)(gy*256+gx)*64 + ci8*8] =
            *(const uint4*)&s_y[px*72 + ci8*8];
    }
}

// ---------------------------------------------------------------------------
// conva: staging split into a uniform enc-loop and a small img-loop
// (removes the %13 divergent indexing); K-loop/epilogue unchanged.
// ---------------------------------------------------------------------------
__global__ __launch_bounds__(256,2) void conva_k(
    const ushort* __restrict__ enc, const float* __restrict__ img,
    const float* __restrict__ dplane, const ushort* __restrict__ wgt, // [9][64][96]
    const float* __restrict__ gamma, const float* __restrict__ beta,
    const float* __restrict__ mean,  const float* __restrict__ var,
    const float* __restrict__ bias,
    const float* __restrict__ Tb,    // [b][64][9]
    const float* __restrict__ wf, const float* __restrict__ bfv,
    float* __restrict__ outp)
{
    __shared__ ushort __align__(16) s_x[18*18*CAST];
    __shared__ float s_al[64], s_be[64];
    __shared__ float s_T[64*9];
    __shared__ float s_wf[3*64];
    __shared__ float s_bf[3];

    const int tid = threadIdx.x;
    const int x0 = blockIdx.x*16, y0 = blockIdx.y*16, b = blockIdx.z;

    if (tid < 64) {
        float a = gamma[tid]*rsqrtf(var[tid]+EPSV);
        s_al[tid] = a; s_be[tid] = (bias[tid]-mean[tid])*a + beta[tid];
    }
    if (tid < 192) s_wf[tid] = wf[tid];
    if (tid < 3)   s_bf[tid] = bfv[tid];
    for (int c = tid; c < 64*9; c += 256) s_T[c] = Tb[(size_t)b*576 + c];

    const size_t ibase = (size_t)b*HWSZ*64;
    // enc channels 0..63 (uniform), ch0 watermark delta folded in
    for (int c = tid; c < 18*18*8; c += 256) {
        int ci8 = c & 7, pp = c >> 3;
        int px = pp % 18, py = pp / 18;
        int gy = y0-1+py, gx = x0-1+px;
        uint4 v = make_uint4(0,0,0,0);
        if ((unsigned)gy < 256u && (unsigned)gx < 256u) {
            v = *(const uint4*)&enc[ibase + (size_t)(gy*256+gx)*64 + ci8*8];
            if (ci8 == 0) {
                float d = dplane[(size_t)b*HWSZ + gy*256 + gx];
                ushort nb = f2b(b2fu((ushort)(v.x & 0xffffu)) + d);
                v.x = (v.x & 0xffff0000u) | (uint)nb;
            }
        }
        *(uint4*)&s_x[(py*18+px)*CAST + ci8*8] = v;
    }
    // img channels 64..66 + zero pads 67..103
    for (int c = tid; c < 18*18*5; c += 256) {
        int ci8 = 8 + c % 5, pp = c / 5;
        int px = pp % 18, py = pp / 18;
        int gy = y0-1+py, gx = x0-1+px;
        uint4 v = make_uint4(0,0,0,0);
        if (ci8 == 8 && (unsigned)gy < 256u && (unsigned)gx < 256u) {
            float i0 = img[((size_t)b*3 + 0)*HWSZ + gy*256 + gx];
            float i1 = img[((size_t)b*3 + 1)*HWSZ + gy*256 + gx];
            float i2 = img[((size_t)b*3 + 2)*HWSZ + gy*256 + gx];
            v.x = (uint)f2b(i0) | ((uint)f2b(i1) << 16);
            v.y = (uint)f2b(i2);
        }
        *(uint4*)&s_x[(py*18+px)*CAST + ci8*8] = v;
    }
    __syncthreads();

    const int lane = tid & 63, wid = tid >> 6;
    const int n16 = lane & 15, quad = lane >> 4;

    floatx4 acc[4][4];
    #pragma unroll
    for (int mi=0;mi<4;mi++)
      #pragma unroll
      for (int ni=0;ni<4;ni++)
        #pragma unroll
        for (int r=0;r<4;r++) acc[mi][ni][r] = 0.f;

    #pragma unroll
    for (int q=0; q<3; q++) {
        #pragma unroll
        for (int kc=0; kc<96; kc+=32) {
            short8 bfr[6];
            #pragma unroll
            for (int rr=0; rr<6; rr++)
                bfr[rr] = *(const short8*)&s_x[((wid*4+rr)*18 + n16+q)*CAST + kc + quad*8];
            short8 af[3][4];
            #pragma unroll
            for (int p=0;p<3;p++)
              #pragma unroll
              for (int mi=0;mi<4;mi++)
                af[p][mi] = *(const short8*)&wgt[((size_t)(p*3+q)*64 + mi*16+n16)*96 + kc + quad*8];
            #pragma unroll
            for (int p=0;p<3;p++)
              #pragma unroll
              for (int mi=0;mi<4;mi++)
                #pragma unroll
                for (int ni=0;ni<4;ni++)
                  acc[mi][ni] = __builtin_amdgcn_mfma_f32_16x16x32_bf16(
                      af[p][mi], bfr[ni+p], acc[mi][ni], 0, 0, 0);
        }
    }

    float po[3][4];
    #pragma unroll
    for (int o=0;o<3;o++)
      #pragma unroll
      for (int ni=0;ni<4;ni++) po[o][ni] = 0.f;

    #pragma unroll
    for (int mi=0;mi<4;mi++) {
        int cob = mi*16 + quad*4;
        #pragma unroll
        for (int r=0;r<4;r++) {
            int co = cob + r;
            float al = s_al[co], be = s_be[co];
            const float* t = &s_T[co*9];
            float w0f = s_wf[0*64+co], w1f = s_wf[1*64+co], w2f = s_wf[2*64+co];
            #pragma unroll
            for (int ni=0;ni<4;ni++) {
                int h = y0 + wid*4 + ni, w = x0 + n16;
                float tv = t[0];
                if (h==0)   tv -= t[1];
                if (h==255) tv -= t[2];
                if (w==0)   tv -= t[3];
                if (w==255) tv -= t[4];
                if (h==0   && w==0)   tv += t[5];
                if (h==0   && w==255) tv += t[6];
                if (h==255 && w==0)   tv += t[7];
                if (h==255 && w==255) tv += t[8];
                float y = fmaxf(al*(acc[mi][ni][r] + tv) + be, 0.f);
                po[0][ni] += w0f*y; po[1][ni] += w1f*y; po[2][ni] += w2f*y;
            }
        }
    }
    #pragma unroll
    for (int o=0;o<3;o++)
      #pragma unroll
      for (int ni=0;ni<4;ni++) {
        float pv = po[o][ni];
        pv += __shfl_xor(pv, 16, 64);
        pv += __shfl_xor(pv, 32, 64);
        if (quad == o) {
            int h = y0 + wid*4 + ni, w = x0 + n16;
            outp[((size_t)b*3 + o)*HWSZ + h*256 + w] = pv + s_bf[o];
        }
      }
}

// ---------------------------------------------------------------------------
// msgterm / idx (unchanged)
// ---------------------------------------------------------------------------
__global__ __launch_bounds__(256) void msgterm_k(const float* __restrict__ msg,
                                                 const float* __restrict__ wa,
                                                 float* __restrict__ Tbuf)
{
    __shared__ float red[256];
    int b = blockIdx.x, o = blockIdx.y, l = threadIdx.x;
    float m = msg[b*NL + l];
    float wv[9];
    #pragma unroll
    for (int t=0;t<9;t++) wv[t] = wa[((size_t)o*323 + l)*9 + t] * m;
    float comp[9];
    comp[0] = wv[0]+wv[1]+wv[2]+wv[3]+wv[4]+wv[5]+wv[6]+wv[7]+wv[8];
    comp[1] = wv[0]+wv[1]+wv[2];
    comp[2] = wv[6]+wv[7]+wv[8];
    comp[3] = wv[0]+wv[3]+wv[6];
    comp[4] = wv[2]+wv[5]+wv[8];
    comp[5] = wv[0]; comp[6]=wv[2]; comp[7]=wv[6]; comp[8]=wv[8];
    for (int cpi=0;cpi<9;cpi++){
        red[l] = comp[cpi];
        __syncthreads();
        for (int s=128;s>0;s>>=1){ if (l<s) red[l]+=red[l+s]; __syncthreads(); }
        if (l==0) Tbuf[((size_t)b*CC+o)*9+cpi] = red[0];
        __syncthreads();
    }
}

__global__ void build_idx_k(int* __restrict__ idx)
{
    if (threadIdx.x==0 && blockIdx.x==0) {
        int n=0;
        for (int i=-10;i<=10;i++)
            for (int j=-10;j<=10;j++) {
                if (n>=NL) return;
                if (i*i+j*j<=100) { idx[2*n]=128+i; idx[2*n+1]=128+j; n++; }
            }
    }
}

// ---------------------------------------------------------------------------
// Separable watermark DFT pipeline.
// ---------------------------------------------------------------------------
__global__ __launch_bounds__(256) void colA_k(const float* __restrict__ plane,
                                              float* __restrict__ Cbuf)
{
    __shared__ float twc[256], tws[256];
    int t = blockIdx.x, b = blockIdx.y, w = threadIdx.x;
    float sv, cv;
    __sincosf(6.283185307179586f * (float)w / 256.0f, &sv, &cv);
    twc[w]=cv; tws[w]=sv;
    __syncthreads();
    int yk = YK0 + t;
    const float* pb = &plane[(size_t)b*HWSZ];
    int m = 0;
    float fr=0.f, fi=0.f;
    for (int h=0; h<256; h++) {
        float xv = pb[h*256 + w];
        fr += xv*twc[m];
        fi -= xv*tws[m];
        m = (m + yk) & 255;
    }
    float* Cb = &Cbuf[((size_t)(b*NYK + t)*2)*256];
    Cb[w]       = fr;
    Cb[256 + w] = fi;
}

// freqB with wave-shuffle reduction (1 barrier instead of 16)
__global__ __launch_bounds__(256) void freqB_k(const float* __restrict__ Cbuf,
                                               const float* __restrict__ msg,
                                               const int* __restrict__ idx,
                                               float* __restrict__ D)
{
    __shared__ float twc[256], tws[256];
    __shared__ float sfr[4], sfi[4];
    int k = blockIdx.x, b = blockIdx.y, w = threadIdx.x;
    float sv, cv;
    __sincosf(6.283185307179586f * (float)w / 256.0f, &sv, &cv);
    twc[w]=cv; tws[w]=sv;
    __syncthreads();
    int yk = idx[2*k], xk = idx[2*k+1];
    int t = yk - YK0;
    const float* Cb = &Cbuf[((size_t)(b*NYK + t)*2)*256];
    float Cr = Cb[w], Ci = Cb[256 + w];
    int ang = (xk*w) & 255;
    float cx = twc[ang], sx = tws[ang];
    float fr = Cr*cx + Ci*sx;
    float fi = Ci*cx - Cr*sx;
    #pragma unroll
    for (int off=32; off>0; off>>=1) {
        fr += __shfl_xor(fr, off, 64);
        fi += __shfl_xor(fi, off, 64);
    }
    if ((w & 63) == 0) { sfr[w>>6] = fr; sfi[w>>6] = fi; }
    __syncthreads();
    if (w == 0) {
        float FR = sfr[0]+sfr[1]+sfr[2]+sfr[3];
        float FI = sfi[0]+sfi[1]+sfi[2]+sfi[3];
        float mv = msg[b*NL + k];
        D[((size_t)b*NL + k)*2 + 0] = mv - FR;
        D[((size_t)b*NL + k)*2 + 1] = mv - FI;
    }
}

__global__ __launch_bounds__(256) void rowC_k(const int* __restrict__ idx,
                                              const float* __restrict__ D,
                                              float* __restrict__ Sbuf)
{
    __shared__ float twc[256], tws[256], dr[256], di[256];
    __shared__ int iy[256], ix[256];
    int t = blockIdx.x, b = blockIdx.y, w = threadIdx.x;
    float sv, cv;
    __sincosf(6.283185307179586f * (float)w / 256.0f, &sv, &cv);
    twc[w]=cv; tws[w]=sv;
    dr[w] = D[((size_t)b*NL + w)*2+0];
    di[w] = D[((size_t)b*NL + w)*2+1];
    iy[w] = idx[2*w]; ix[w] = idx[2*w+1];
    __syncthreads();
    int yk = YK0 + t;
    float Sr=0.f, Si=0.f;
    for (int k=0;k<256;k++) {
        if (iy[k] != yk) continue;           // wave-uniform branch
        int ang = (ix[k]*w) & 255;
        float c = twc[ang], s = tws[ang];
        Sr += dr[k]*c - di[k]*s;
        Si += dr[k]*s + di[k]*c;
    }
    float* Sb = &Sbuf[((size_t)(b*NYK + t)*2)*256];
    Sb[w]       = Sr;
    Sb[256 + w] = Si;
}

__global__ __launch_bounds__(256) void applyD_k(const float* __restrict__ Sbuf,
                                                float* __restrict__ dplane)
{
    __shared__ float twc[256], tws[256];
    int h = blockIdx.x, b = blockIdx.y, w = threadIdx.x;
    float sv, cv;
    __sincosf(6.283185307179586f * (float)w / 256.0f, &sv, &cv);
    twc[w]=cv; tws[w]=sv;
    __syncthreads();
    float acc = 0.f;
    #pragma unroll
    for (int t=0;t<NYK;t++) {
        int yk = YK0 + t;
        int ang = (yk*h) & 255;              // wave-uniform
        float cy = twc[ang], sy = tws[ang];
        const float* Sb = &Sbuf[((size_t)(b*NYK + t)*2)*256];
        acc += cy*Sb[w] - sy*Sb[256 + w];
    }
    dplane[(size_t)b*HWSZ + h*256 + w] = acc * (1.0f/65536.0f);
}

// ---------------------------------------------------------------------------
extern "C" void kernel_launch(void* const* d_in, const int* in_sizes, int n_in,
                              void* d_out, int out_size, void* d_ws, size_t ws_size,
                              hipStream_t stream)
{
    const float* image = (const float*)d_in[0];
    const float* msg   = (const float*)d_in[1];
    const float* w0    = (const float*)d_in[2];
    const float* b0    = (const float*)d_in[3];
    const float* g0    = (const float*)d_in[4];
    const float* be0   = (const float*)d_in[5];
    const float* m0    = (const float*)d_in[6];
    const float* v0    = (const float*)d_in[7];
    const float* wk    = (const float*)d_in[8];
    const float* bk    = (const float*)d_in[9];
    const float* gk    = (const float*)d_in[10];
    const float* bek   = (const float*)d_in[11];
    const float* mk    = (const float*)d_in[12];
    const float* vk    = (const float*)d_in[13];
    const float* wa    = (const float*)d_in[14];
    const float* ba    = (const float*)d_in[15];
    const float* ga    = (const float*)d_in[16];
    const float* bea   = (const float*)d_in[17];
    const float* ma    = (const float*)d_in[18];
    const float* va    = (const float*)d_in[19];
    const float* wf    = (const float*)d_in[20];
    const float* bfv   = (const float*)d_in[21];
    float* out = (float*)d_out;

    // Tightened layout (12 MB header) so chunk=16 fits if ws >= ~280 MB.
    char* base = (char*)d_ws;
    int*    idx    = (int*)base;                              // 2 KB
    float*  Dbuf   = (float*)(base + (4<<10));                // 32 KB
    float*  Tbuf   = (float*)(base + (40<<10));               // 36 KB
    ushort* wkb2   = (ushort*)(base + (128<<10));             // 216 KB
    ushort* wab2   = (ushort*)(base + (384<<10));             // 108 KB
    float*  Cbuf   = (float*)(base + (512<<10));              // 512 KB
    float*  Sbuf   = (float*)(base + ((size_t)1<<20));        // 512 KB
    float*  plane  = (float*)(base + ((size_t)2<<20));        // 4.2 MB
    float*  dplane = (float*)(base + ((size_t)7<<20));        // 4.2 MB
    ushort* bufA   = (ushort*)(base + ((size_t)12<<20));

    const size_t perB = (size_t)HWSZ*64*2*2;  // 16.8 MB: both bf16 buffers / batch
    int chunk = 1;
    for (int c = NB; c >= 1; c >>= 1)
        if (((size_t)12<<20) + (size_t)c*perB <= ws_size) { chunk = c; break; }
    ushort* bufB = bufA + (size_t)chunk*HWSZ*64;

    build_idx_k<<<1,64,0,stream>>>(idx);
    msgterm_k<<<dim3(NB,CC),256,0,stream>>>(msg, wa, Tbuf);
    int prep_n = (3*9*64*64 + 9*64*96 + 255)/256;
    prep_w_k<<<prep_n,256,0,stream>>>(wk, wa, wkb2, wab2);

    const size_t WL = (size_t)9*64*64;  // one layer of wkb2

    for (int cs = 0; cs < NB; cs += chunk) {
        dim3 g(16,16,chunk);
        const float* img_c = image + (size_t)cs*3*HWSZ;

        conv0_k<<<g,256,0,stream>>>(img_c, w0, b0, g0, be0, m0, v0, bufA);
        convm_k<<<g,256,0,stream>>>(bufA, wkb2 + 0*WL, bufB,
            gk+0*CC, bek+0*CC, mk+0*CC, vk+0*CC, bk+0*CC, nullptr);
        convm_k<<<g,256,0,stream>>>(bufB, wkb2 + 1*WL, bufA,
            gk+1*CC, bek+1*CC, mk+1*CC, vk+1*CC, bk+1*CC, nullptr);
        convm_k<<<g,256,0,stream>>>(bufA, wkb2 + 2*WL, bufB,
            gk+2*CC, bek+2*CC, mk+2*CC, vk+2*CC, bk+2*CC, plane);

        // separable watermark DFT (forward + inverse)
        colA_k<<<dim3(NYK,chunk),256,0,stream>>>(plane, Cbuf);
        freqB_k<<<dim3(NL,chunk),256,0,stream>>>(Cbuf, msg + (size_t)cs*NL, idx, Dbuf);
        rowC_k<<<dim3(NYK,chunk),256,0,stream>>>(idx, Dbuf, Sbuf);
        applyD_k<<<dim3(HH,chunk),256,0,stream>>>(Sbuf, dplane);

        conva_k<<<g,256,0,stream>>>(bufB, img_c, dplane, wab2,
            ga, bea, ma, va, ba, Tbuf + (size_t)cs*CC*9, wf, bfv,
            out + (size_t)cs*3*HWSZ);
    }
}